// Round 1
// 260.360 us; speedup vs baseline: 1.3750x; 1.3750x over previous
//
#include <hip/hip_runtime.h>
#include <math.h>

#define NCLS 19
#define HW   (512*1024)          // 524288
#define CHW  (NCLS*HW)
#define TPIX (2*HW)              // 1048576
#define NB   512                 // coarse bins: LDS-private hist fits 19*512*4 = 38912 B
#define NPART 16                 // partial histogram copies (blocks of k1b)
#define CAND_MAX 4096

// ---- workspace layout (bytes) ----
// NPART partial hists exactly fill the old 8192-bin hist slot: 16*19*512*4 = 622592
#define WS_PART   0
#define WS_CANDC  622592                     // NCLS*4 candidate counters
#define WS_ACCUM  622720                     // [0]=sum_loss f32, [1]=cnt_mask u32, [2]=cnt_solid u32
#define WS_ZSTART 622592                     // memset range start (cand_cnt + accum only)
#define WS_ZSIZE  256
#define WS_SEL    622848                     // NCLS * {int bin, int rank}
#define WS_NEWTH  623360                     // NCLS*4
#define WS_CONF   623616                     // TPIX*4
#define WS_LOSS   4817920                    // TPIX*4
#define WS_LABEL  9012224                    // TPIX*1
#define WS_CAND   10060800                   // NCLS*CAND_MAX*4 -> end 10372096

// ---------------- K1: async LDS staging + per-pixel softmax stats ----------------
// R4 change: NO histogram atomic here. The 1M scattered device-scope atomicAdds
// were far-atomics at the fabric (32B each -> the 32MB of excess WRITE_SIZE) and
// backpressured the DMA stream. K1 is now pure streaming.
#define WAVE_PX 64
#define WPB 4                        // waves per block
__global__ __launch_bounds__(256)
void k1_pixel(const float* __restrict__ lb_t, const float* __restrict__ la_t,
              float* __restrict__ conf_o, float* __restrict__ loss_o,
              unsigned char* __restrict__ label_o)
{
    __shared__ float smem[WPB * 2 * NCLS * WAVE_PX];   // 4*38*64*4B = 38912 B -> 4 blocks/CU
    const int tid  = threadIdx.x;
    const int wave = tid >> 6;
    const int lane = tid & 63;
    const int tile = blockIdx.x * WPB + wave;          // 16384 wave-tiles
    const int pix  = tile * WAVE_PX + lane;
    const int n    = pix >> 19;                        // pix / HW
    const int rem  = pix & (HW - 1);
    const float* lb = lb_t + (size_t)n * CHW + rem;    // lane-contiguous
    const float* la = la_t + (size_t)n * CHW + rem;
    float* sw = &smem[wave * (2 * NCLS * WAVE_PX)];    // per-wave private region

#pragma unroll
    for (int c = 0; c < NCLS; ++c) {
        __builtin_amdgcn_global_load_lds(
            (__attribute__((address_space(1))) void*)(lb + (size_t)c * HW),
            (__attribute__((address_space(3))) void*)(sw + c * WAVE_PX),
            4, 0, 0);
    }
#pragma unroll
    for (int c = 0; c < NCLS; ++c) {
        __builtin_amdgcn_global_load_lds(
            (__attribute__((address_space(1))) void*)(la + (size_t)c * HW),
            (__attribute__((address_space(3))) void*)(sw + (NCLS + c) * WAVE_PX),
            4, 0, 0);
    }
    asm volatile("s_waitcnt vmcnt(0)" ::: "memory");   // wave-local: no barrier needed

    float mb, zb, dot, a_lab, ma, za; int lab;
    {
        float bb = sw[lane];
        float aa = sw[NCLS * WAVE_PX + lane];
        mb = bb; zb = 1.0f; dot = aa; lab = 0; a_lab = aa; ma = aa; za = 1.0f;
    }
#pragma unroll
    for (int c = 1; c < NCLS; ++c) {
        float b = sw[c * WAVE_PX + lane];
        float a = sw[(NCLS + c) * WAVE_PX + lane];
        // before-softmax online (max, Z, dot(pb_unnorm, la))
        float mn = fmaxf(mb, b);
        float eo = __expf(mb - mn);
        float en = __expf(b - mn);
        zb  = zb * eo + en;
        dot = dot * eo + en * a;
        bool upd = b > mb;                  // first-max-wins (strict >)
        lab   = upd ? c : lab;
        a_lab = upd ? a : a_lab;
        mb = mn;
        // after-softmax online (max, Z)
        float mna = fmaxf(ma, a);
        za = za * __expf(ma - mna) + __expf(a - mna);
        ma = mna;
    }

    float cf = 1.0f / zb;                               // max softmax prob
    float pa_lab = __expf(a_lab - ma) / za;
    float ls = (1.0f - pa_lab) * (ma + __logf(za) - dot / zb);

    conf_o[pix]  = cf;
    loss_o[pix]  = ls;
    label_o[pix] = (unsigned char)lab;
}

// ---------------- K1b: LDS-private histograms, zero global atomics ----------------
// 16 blocks, each owns 65536 px, builds a private 19x512 u32 hist in LDS (LDS
// atomics only), then stores its copy to its partial slot (plain coalesced writes).
__global__ __launch_bounds__(256)
void k1b_hist(const float4* __restrict__ conf, const uchar4* __restrict__ label,
              unsigned int* __restrict__ part)
{
    __shared__ unsigned int lh[NCLS * NB];             // 38912 B
    const int t = threadIdx.x;
    for (int w = t; w < NCLS * NB; w += 256) lh[w] = 0u;
    __syncthreads();

    const int per_blk4 = TPIX / 4 / NPART;             // 16384 float4 per block
    const int base4 = blockIdx.x * per_blk4;
    for (int i = 0; i < per_blk4 / 256; ++i) {         // 64 iterations
        int g = base4 + i * 256 + t;
        float4 c4 = conf[g];
        uchar4 l4 = label[g];
        float cf[4] = {c4.x, c4.y, c4.z, c4.w};
        int   lb[4] = {l4.x, l4.y, l4.z, l4.w};
#pragma unroll
        for (int k = 0; k < 4; ++k) {
            int bin = (int)(cf[k] * (float)NB);
            bin = bin < (NB - 1) ? bin : (NB - 1);
            atomicAdd(&lh[lb[k] * NB + bin], 1u);      // LDS atomic: fast
        }
    }
    __syncthreads();

    unsigned int* dst = part + blockIdx.x * (NCLS * NB);
    for (int w = t; w < NCLS * NB; w += 256) dst[w] = lh[w];
}

// ---------------- K2: reduce partials + per-class rank -> (bin, rank-in-bin) ----------------
__global__ __launch_bounds__(256)
void k2_select(const unsigned int* __restrict__ part, const float* __restrict__ cls_thresh,
               int* __restrict__ sel, unsigned int* __restrict__ cand_cnt,
               float* __restrict__ cand)
{
    int c = blockIdx.x;
    int t = threadIdx.x;
    float thr = cls_thresh[c];
    int thr_bin = (int)(thr * (float)NB); thr_bin = thr_bin < (NB-1) ? thr_bin : (NB-1);

    // thread t owns DESCENDING chunk of 2 bins: [NB-(t+1)*2, NB-t*2)
    int base = NB - (t + 1) * 2;
    unsigned h0 = 0, h1 = 0;
    for (int b = 0; b < NPART; ++b) {
        const unsigned int* p = part + b * (NCLS * NB) + c * NB;
        h0 += p[base];
        h1 += p[base + 1];
    }
    if (base == thr_bin)     h0 += 1u;                 // extended multiset: append thr
    if (base + 1 == thr_bin) h1 += 1u;
    unsigned s = h0 + h1;

    __shared__ unsigned sc[256];
    sc[t] = s;
    __syncthreads();
    for (int off = 1; off < 256; off <<= 1) {
        unsigned vt = sc[t];
        unsigned vp = (t >= off) ? sc[t - off] : 0u;
        __syncthreads();
        sc[t] = vt + vp;
        __syncthreads();
    }
    unsigned total_ext = sc[255];                      // count_c + 1
    unsigned cnt = total_ext - 1u;
    int idx = (int)floorf((float)(cnt + 1u) * 0.2f * powf(thr, 8.0f));

    unsigned above = sc[t] - s;                        // strictly above this chunk
    if ((unsigned)idx >= above && (unsigned)idx < above + s) {
        int B, r;
        if ((unsigned)idx < above + h1) { B = base + 1; r = (int)((unsigned)idx - above); }
        else                            { B = base;     r = (int)((unsigned)idx - above - h1); }
        sel[2 * c]     = B;
        sel[2 * c + 1] = r;
        if (B == thr_bin) {                            // the appended thr is a candidate
            unsigned pos = atomicAdd(&cand_cnt[c], 1u);
            if (pos < CAND_MAX) cand[c * CAND_MAX + pos] = thr;
        }
    }
}

// ---------------- K3: gather candidates in selection bin (4 px/thread) ----------------
__global__ __launch_bounds__(256)
void k3_gather(const float4* __restrict__ conf, const uchar4* __restrict__ label,
               const int* __restrict__ sel, unsigned int* __restrict__ cand_cnt,
               float* __restrict__ cand)
{
    int g = blockIdx.x * 256 + threadIdx.x;
    float4 c4 = conf[g];
    uchar4 l4 = label[g];
    float cf[4] = {c4.x, c4.y, c4.z, c4.w};
    int   lb[4] = {l4.x, l4.y, l4.z, l4.w};
#pragma unroll
    for (int i = 0; i < 4; ++i) {
        int bin = (int)(cf[i] * (float)NB);
        bin = bin < (NB - 1) ? bin : (NB - 1);
        if (bin == sel[2 * lb[i]]) {
            unsigned pos = atomicAdd(&cand_cnt[lb[i]], 1u);
            if (pos < CAND_MAX) cand[lb[i] * CAND_MAX + pos] = cf[i];
        }
    }
}

// ---------------- K4: exact rank among candidates -> new_thresh ----------------
__global__ __launch_bounds__(256)
void k4_thresh(const int* __restrict__ sel, const unsigned int* __restrict__ cand_cnt,
               const float* __restrict__ cand, const float* __restrict__ cls_thresh,
               float* __restrict__ newth)
{
    int c = blockIdx.x;
    int t = threadIdx.x;
    unsigned mc = cand_cnt[c];
    int m = (int)(mc < (unsigned)CAND_MAX ? mc : (unsigned)CAND_MAX);
    int r = sel[2 * c + 1];

    __shared__ float v[CAND_MAX];
    __shared__ float result;
    for (int i = t; i < m; i += 256) v[i] = cand[c * CAND_MAX + i];
    __syncthreads();

    for (int i = t; i < m; i += 256) {
        float x = v[i];
        int gcnt = 0, e = 0;
        for (int j = 0; j < m; ++j) {
            gcnt += (v[j] > x);
            e    += (v[j] == x);
        }
        if (gcnt <= r && r < gcnt + e) result = x;   // duplicates write same value
    }
    __syncthreads();
    if (t == 0) {
        float thr = cls_thresh[c];
        float nt = 0.9f * thr + 0.1f * result;
        if (nt >= 1.0f) nt = 0.999f;
        newth[c] = nt;
    }
}

// ---------------- K5: masked reduction (4 px/thread) ----------------
__global__ __launch_bounds__(256)
void k5_reduce(const float4* __restrict__ conf, const float4* __restrict__ loss,
               const uchar4* __restrict__ label, const float* __restrict__ newth,
               float* __restrict__ accum)
{
    __shared__ float th[NCLS];
    if (threadIdx.x < NCLS) th[threadIdx.x] = newth[threadIdx.x];
    __syncthreads();

    int g = blockIdx.x * 256 + threadIdx.x;
    float4 c4 = conf[g];
    float4 s4 = loss[g];
    uchar4 l4 = label[g];
    float cf[4] = {c4.x, c4.y, c4.z, c4.w};
    float lv[4] = {s4.x, s4.y, s4.z, s4.w};
    int   lb[4] = {l4.x, l4.y, l4.z, l4.w};

    float ls = 0.0f; int mask = 0, solid = 0;
#pragma unroll
    for (int i = 0; i < 4; ++i) {
        bool m = cf[i] > th[lb[i]];
        mask  += m ? 1 : 0;
        solid += (cf[i] > 0.8f) ? 1 : 0;
        ls    += m ? fmaxf(lv[i], 1e-8f) : 0.0f;
    }

    for (int off = 32; off > 0; off >>= 1) {
        ls    += __shfl_down(ls, off, 64);
        mask  += __shfl_down(mask, off, 64);
        solid += __shfl_down(solid, off, 64);
    }
    __shared__ float s_ls[4];
    __shared__ int   s_m[4], s_s[4];
    int w = threadIdx.x >> 6;
    if ((threadIdx.x & 63) == 0) { s_ls[w] = ls; s_m[w] = mask; s_s[w] = solid; }
    __syncthreads();
    if (threadIdx.x == 0) {
        float L = s_ls[0] + s_ls[1] + s_ls[2] + s_ls[3];
        int   M = s_m[0] + s_m[1] + s_m[2] + s_m[3];
        int   S = s_s[0] + s_s[1] + s_s[2] + s_s[3];
        atomicAdd(&accum[0], L);
        atomicAdd(&((unsigned int*)accum)[1], (unsigned)M);
        atomicAdd(&((unsigned int*)accum)[2], (unsigned)S);
    }
}

// ---------------- K6: write outputs ----------------
__global__ void k6_out(const float* __restrict__ accum, float* __restrict__ out)
{
    float sum = accum[0];
    unsigned cm = ((const unsigned int*)accum)[1];
    unsigned cs = ((const unsigned int*)accum)[2];
    float den = fmaxf((float)cm, 1.0f);
    out[0] = sum / den;
    out[1] = (float)cm / (float)TPIX;
    out[2] = (float)cs / (float)TPIX;
}

extern "C" void kernel_launch(void* const* d_in, const int* in_sizes, int n_in,
                              void* d_out, int out_size, void* d_ws, size_t ws_size,
                              hipStream_t stream)
{
    const float* lb  = (const float*)d_in[0];
    const float* la  = (const float*)d_in[1];
    const float* cth = (const float*)d_in[2];
    float* out = (float*)d_out;

    char* ws = (char*)d_ws;
    unsigned int* part     = (unsigned int*)(ws + WS_PART);
    unsigned int* cand_cnt = (unsigned int*)(ws + WS_CANDC);
    float*        accum    = (float*)(ws + WS_ACCUM);
    int*          sel      = (int*)(ws + WS_SEL);
    float*        newth    = (float*)(ws + WS_NEWTH);
    float*        conf     = (float*)(ws + WS_CONF);
    float*        loss     = (float*)(ws + WS_LOSS);
    unsigned char* label   = (unsigned char*)(ws + WS_LABEL);
    float*        cand     = (float*)(ws + WS_CAND);

    hipMemsetAsync(ws + WS_ZSTART, 0, WS_ZSIZE, stream);  // cand_cnt + accum only

    dim3 blk(256);
    dim3 grd1(TPIX / (WPB * WAVE_PX));   // 4096 blocks, 1 px/thread via LDS tiles
    dim3 grd4(TPIX / 4 / 256);           // 1024 blocks, 4 px/thread

    k1_pixel<<<grd1, blk, 0, stream>>>(lb, la, conf, loss, label);
    k1b_hist<<<NPART, blk, 0, stream>>>((const float4*)conf, (const uchar4*)label, part);
    k2_select<<<NCLS, blk, 0, stream>>>(part, cth, sel, cand_cnt, cand);
    k3_gather<<<grd4, blk, 0, stream>>>((const float4*)conf, (const uchar4*)label,
                                        sel, cand_cnt, cand);
    k4_thresh<<<NCLS, blk, 0, stream>>>(sel, cand_cnt, cand, cth, newth);
    k5_reduce<<<grd4, blk, 0, stream>>>((const float4*)conf, (const float4*)loss,
                                        (const uchar4*)label, newth, accum);
    k6_out<<<1, 1, 0, stream>>>(accum, out);
}